// Round 3
// baseline (11101.089 us; speedup 1.0000x reference)
//
#include <hip/hip_runtime.h>

// ---------------------------------------------------------------------------
// XiRNN (peephole LSTM) on MI355X.  B=64, T=188, I=512, H=R=1024.
//   k_prep : fp32->bf16 conversion; W_rec split into bf16 hi+lo; zero flags.
//   k_px   : px[t][gate][j][b] = x[b,t,:]·W_ih[gate*H+j,:] + bias (MFMA GEMM)
//   k_scan : persistent kernel, 256 blocks (1/CU, REGULAR launch — coop launch
//            silently fails in this harness), 4 batch-groups of 16 rows x 64
//            CUs. Weights VGPR-resident. Peephole computed in compensated
//            bf16: c_hi@W_hi + c_hi@W_lo + c_lo@W_hi (c runs to ~450; plain
//            bf16 peephole loses ~0.5 absolute). c kept fp32 in LDS locally;
//            cross-CU state in bf16 (c split hi/lo). Per-step sync via
//            per-wave flags, agent-scope atomics (no grid.sync needed).
// ---------------------------------------------------------------------------

#define T_N 188

// ws byte offsets (256-aligned). Total = 132,648,960 B (~126.5 MiB).
#define WS_PX     0UL           // ushort[188*4096*64]   = 98,566,144 B
#define WS_XB     98566144UL    // ushort[64*188*512]    = 12,320,768 B
#define WS_WIHB   110886912UL   // ushort[4096*512]      =  4,194,304 B
#define WS_WCOMB  115081216UL   // ushort[6144*1024]     = 12,582,912 B
#define WS_HST    127664128UL   // ushort[2][64][1024]   =    262,144 B
#define WS_CST    127926272UL   // ushort[2][64][1024]   =    262,144 B
#define WS_FLAGS  128188416UL   // int[1024]             =      4,096 B
#define WS_WRECLO 128192512UL   // ushort[2048*1024]     =  4,194,304 B
#define WS_CSTLO  132386816UL   // ushort[2][64][1024]   =    262,144 B

typedef __attribute__((ext_vector_type(8))) short short8;
typedef __attribute__((ext_vector_type(4))) float f4;

__device__ __forceinline__ float b2f(unsigned short u) {
    union { unsigned int i; float f; } v; v.i = ((unsigned int)u) << 16; return v.f;
}
__device__ __forceinline__ unsigned short f2b(float f) {
    unsigned int u = __float_as_uint(f);
    return (unsigned short)((u + 0x7FFFu + ((u >> 16) & 1u)) >> 16);
}
__device__ __forceinline__ float sigf(float x) { return 1.0f / (1.0f + __expf(-x)); }
__device__ __forceinline__ float tanh_(float x) {
    float e = __expf(2.0f * x); return 1.0f - 2.0f / (e + 1.0f);
}
#define MFMA(a, b, c) __builtin_amdgcn_mfma_f32_16x16x32_bf16((a), (b), (c), 0, 0, 0)

// 16B state load through LLC (agent scope -> coherent across XCDs)
__device__ __forceinline__ short8 ld_state(const unsigned short* p) {
    union { unsigned long long u[2]; short8 v; } r;
    r.u[0] = __hip_atomic_load((unsigned long long*)p,     __ATOMIC_RELAXED, __HIP_MEMORY_SCOPE_AGENT);
    r.u[1] = __hip_atomic_load((unsigned long long*)p + 1, __ATOMIC_RELAXED, __HIP_MEMORY_SCOPE_AGENT);
    return r.v;
}

__device__ __forceinline__ f4 px_init(const unsigned short* px, int t, int gate, int jg, int brow) {
    unsigned long long pv =
        *(const unsigned long long*)(px + ((long)(t * 4 + gate) * 1024 + jg) * 64 + brow);
    f4 r;
    r[0] = b2f((unsigned short)pv);
    r[1] = b2f((unsigned short)(pv >> 16));
    r[2] = b2f((unsigned short)(pv >> 32));
    r[3] = b2f((unsigned short)(pv >> 48));
    return r;
}

// ---------------------------------------------------------------------------
__global__ void k_prep(const float* __restrict__ x, const float* __restrict__ h0,
                       const float* __restrict__ c0, const float* __restrict__ wih,
                       const float* __restrict__ whh, const float* __restrict__ wrec,
                       unsigned short* __restrict__ xb, unsigned short* __restrict__ wihb,
                       unsigned short* __restrict__ wcomb, unsigned short* __restrict__ hst,
                       unsigned short* __restrict__ cst, unsigned short* __restrict__ wreclo,
                       unsigned short* __restrict__ cstlo, int* __restrict__ flags) {
    const long NX4 = 1540096, NWIH4 = 524288, NWHH4 = 1048576, NWREC4 = 524288, NH4 = 16384;
    const long total = NX4 + NWIH4 + NWHH4 + NWREC4 + NH4 + NH4;
    long gtid = (long)blockIdx.x * blockDim.x + threadIdx.x;
    for (long i = gtid; i < total; i += (long)gridDim.x * blockDim.x) {
        const float* src; unsigned short* dst; unsigned short* lo_dst = nullptr; long off = i;
        if (off < NX4)                   { src = x;    dst = xb; }
        else if ((off -= NX4) < NWIH4)   { src = wih;  dst = wihb; }
        else if ((off -= NWIH4) < NWHH4) { src = whh;  dst = wcomb; }
        else if ((off -= NWHH4) < NWREC4){ src = wrec; dst = wcomb + 4194304; lo_dst = wreclo; }
        else if ((off -= NWREC4) < NH4)  { src = h0;   dst = hst + 65536; }     // state slot 1
        else { off -= NH4;                 src = c0;   dst = cst + 65536; lo_dst = cstlo + 65536; }
        float4 v = ((const float4*)src)[off];
        unsigned short hx = f2b(v.x), hy = f2b(v.y), hz = f2b(v.z), hw = f2b(v.w);
        unsigned long long o = (unsigned long long)hx
            | ((unsigned long long)hy << 16)
            | ((unsigned long long)hz << 32)
            | ((unsigned long long)hw << 48);
        *(unsigned long long*)(dst + off * 4) = o;
        if (lo_dst) {
            unsigned long long l = (unsigned long long)f2b(v.x - b2f(hx))
                | ((unsigned long long)f2b(v.y - b2f(hy)) << 16)
                | ((unsigned long long)f2b(v.z - b2f(hz)) << 32)
                | ((unsigned long long)f2b(v.w - b2f(hw)) << 48);
            *(unsigned long long*)(lo_dst + off * 4) = l;
        }
    }
    if (gtid < 1024) flags[gtid] = 0;
}

// ---------------------------------------------------------------------------
// px GEMM: block = (t, 64-col slab), 4 waves, each wave one 16-col tile, M=64.
__global__ void __launch_bounds__(256) k_px(const unsigned short* __restrict__ xb,
                                            const unsigned short* __restrict__ wihb,
                                            const float* __restrict__ bias,
                                            unsigned short* __restrict__ px) {
    const int t = blockIdx.y;
    const int wv = threadIdx.x >> 6, lane = threadIdx.x & 63;
    const int col = lane & 15, quad = lane >> 4;
    const int n = blockIdx.x * 64 + wv * 16 + col;   // 0..4095 combined gate*H+j
    const float bn = bias[n];
    f4 acc[4];
#pragma unroll
    for (int mt = 0; mt < 4; ++mt) { acc[mt][0] = bn; acc[mt][1] = bn; acc[mt][2] = bn; acc[mt][3] = bn; }
    const unsigned short* bp = wihb + n * 512 + quad * 8;
#pragma unroll 4
    for (int kk = 0; kk < 16; ++kk) {
        short8 bf = *(const short8*)(bp + kk * 32);
#pragma unroll
        for (int mt = 0; mt < 4; ++mt) {
            const unsigned short* ap = xb + ((mt * 16 + col) * 188 + t) * 512 + kk * 32 + quad * 8;
            short8 af = *(const short8*)ap;
            acc[mt] = MFMA(af, bf, acc[mt]);
        }
    }
    const long pb = ((long)(t * 4 + (n >> 10)) * 1024 + (n & 1023)) * 64;
#pragma unroll
    for (int mt = 0; mt < 4; ++mt) {
        unsigned long long o = (unsigned long long)f2b(acc[mt][0])
            | ((unsigned long long)f2b(acc[mt][1]) << 16)
            | ((unsigned long long)f2b(acc[mt][2]) << 32)
            | ((unsigned long long)f2b(acc[mt][3]) << 48);
        *(unsigned long long*)(px + pb + mt * 16 + quad * 4) = o;
    }
}

// ---------------------------------------------------------------------------
// Persistent scan. cu = blockIdx: group g = cu>>6 (16 batch rows), cig = cu&63
// (16 hidden indices). 4 waves: kh = wv>>1 (K-half), ts = wv&1.
//   ts0: tiles {i,f,g,o}, A = h (bf16), W rows 0..4095.
//   ts1: tiles {ri,rf} compensated: c_hi@W_hi + c_hi@W_lo + c_lo@W_hi.
__global__ void __launch_bounds__(256, 1) k_scan(
    const unsigned short* __restrict__ wcomb, const unsigned short* __restrict__ wreclo,
    const float* __restrict__ c0, const int* __restrict__ lengths,
    const unsigned short* __restrict__ px, unsigned short* __restrict__ hst,
    unsigned short* __restrict__ cst, unsigned short* __restrict__ cstlo,
    int* __restrict__ flags, float* __restrict__ out) {
    const int cu = blockIdx.x;
    const int g = cu >> 6, cig = cu & 63;
    const int jbase = cig * 16, b0 = g * 16;
    const int tid = threadIdx.x, wv = tid >> 6, lane = tid & 63;
    const int kh = wv >> 1, ts = wv & 1;
    const int kbase = kh * 512;
    const int col = lane & 15, quad = lane >> 4;

    __shared__ float pre[2][2][6][16][16];   // [slot][kh][tile][b][j]  24 KB
    __shared__ float c_loc[16][16];          // fp32 local c (never rounded)

    // One-time: weights -> VGPRs (4 tiles x 16 k-chunks x 16B/lane = 256 regs)
    short8 wf[4][16];
#pragma unroll
    for (int tile = 0; tile < 4; ++tile) {
        // ts0: rows {0,1,2,3}*1024 (i,f,g,o from W_hh).
        // ts1: wf[0]=ri_hi (row 4096+), wf[1]=rf_hi (row 5120+),
        //      wf[2]=ri_lo, wf[3]=rf_lo (from wreclo rows 0/1024).
        const unsigned short* src;
        if (ts == 0) {
            src = wcomb + (long)(tile * 1024 + jbase + col) * 1024 + kbase + quad * 8;
        } else if (tile < 2) {
            src = wcomb + (long)((4 + tile) * 1024 + jbase + col) * 1024 + kbase + quad * 8;
        } else {
            src = wreclo + (long)((tile - 2) * 1024 + jbase + col) * 1024 + kbase + quad * 8;
        }
#pragma unroll
        for (int kk = 0; kk < 16; ++kk) wf[tile][kk] = *(const short8*)(src + kk * 32);
    }
    {
        int b = tid >> 4, j = tid & 15;
        c_loc[b][j] = c0[(b0 + b) * 1024 + jbase + j];
    }
    const int my_len = lengths[b0 + (tid >> 4)];
    __syncthreads();

    const int fl_base = g * 256;             // this group's 64 CUs x 4 wave-flags
    float* out_h = out;
    float* out_c = out + 12320768;

    for (int t = 0; t < T_N; ++t) {
        const int sl_r = (t + 1) & 1, sl_w = t & 1, ps = t & 1;

        if (t > 0) {
            int* fp = flags + fl_base + lane * 4;
            for (;;) {
                int a0 = __hip_atomic_load(fp + 0, __ATOMIC_RELAXED, __HIP_MEMORY_SCOPE_AGENT);
                int a1 = __hip_atomic_load(fp + 1, __ATOMIC_RELAXED, __HIP_MEMORY_SCOPE_AGENT);
                int a2 = __hip_atomic_load(fp + 2, __ATOMIC_RELAXED, __HIP_MEMORY_SCOPE_AGENT);
                int a3 = __hip_atomic_load(fp + 3, __ATOMIC_RELAXED, __HIP_MEMORY_SCOPE_AGENT);
                if (__all((a0 >= t) && (a1 >= t) && (a2 >= t) && (a3 >= t))) break;
                __builtin_amdgcn_s_sleep(1);
            }
            __threadfence();  // acquire side
        }

        const int sbase = sl_r * 65536 + (b0 + col) * 1024 + kbase + quad * 8;

        if (ts == 0) {
            const unsigned short* hp = hst + sbase;
            f4 acc[4];
#pragma unroll
            for (int tile = 0; tile < 4; ++tile) {
                if (kh == 0) acc[tile] = px_init(px, t, tile, jbase + col, b0 + quad * 4);
                else { acc[tile][0] = 0.f; acc[tile][1] = 0.f; acc[tile][2] = 0.f; acc[tile][3] = 0.f; }
            }
#pragma unroll
            for (int kk = 0; kk < 16; ++kk) {
                short8 af = ld_state(hp + kk * 32);
                acc[0] = MFMA(af, wf[0][kk], acc[0]);
                acc[1] = MFMA(af, wf[1][kk], acc[1]);
                acc[2] = MFMA(af, wf[2][kk], acc[2]);
                acc[3] = MFMA(af, wf[3][kk], acc[3]);
            }
#pragma unroll
            for (int tile = 0; tile < 4; ++tile)
#pragma unroll
                for (int r = 0; r < 4; ++r) pre[ps][kh][tile][quad * 4 + r][col] = acc[tile][r];
        } else {
            const unsigned short* cph = cst + sbase;
            const unsigned short* cpl = cstlo + sbase;
            f4 acc[2];
            acc[0][0] = 0.f; acc[0][1] = 0.f; acc[0][2] = 0.f; acc[0][3] = 0.f;
            acc[1][0] = 0.f; acc[1][1] = 0.f; acc[1][2] = 0.f; acc[1][3] = 0.f;
#pragma unroll
            for (int kk = 0; kk < 16; ++kk) {
                short8 ch = ld_state(cph + kk * 32);
                short8 cl = ld_state(cpl + kk * 32);
                acc[0] = MFMA(ch, wf[0][kk], acc[0]);   // c_hi @ ri_hi
                acc[0] = MFMA(ch, wf[2][kk], acc[0]);   // c_hi @ ri_lo
                acc[0] = MFMA(cl, wf[0][kk], acc[0]);   // c_lo @ ri_hi
                acc[1] = MFMA(ch, wf[1][kk], acc[1]);   // c_hi @ rf_hi
                acc[1] = MFMA(ch, wf[3][kk], acc[1]);   // c_hi @ rf_lo
                acc[1] = MFMA(cl, wf[1][kk], acc[1]);   // c_lo @ rf_hi
            }
#pragma unroll
            for (int tile = 0; tile < 2; ++tile)
#pragma unroll
                for (int r = 0; r < 4; ++r) pre[ps][kh][4 + tile][quad * 4 + r][col] = acc[tile][r];
        }
        __syncthreads();
        {
            const int b = tid >> 4, j = tid & 15;
            float pi = pre[ps][0][0][b][j] + pre[ps][1][0][b][j] + pre[ps][0][4][b][j] + pre[ps][1][4][b][j];
            float pf = pre[ps][0][1][b][j] + pre[ps][1][1][b][j] + pre[ps][0][5][b][j] + pre[ps][1][5][b][j];
            float pg = pre[ps][0][2][b][j] + pre[ps][1][2][b][j];
            float po = pre[ps][0][3][b][j] + pre[ps][1][3][b][j];
            const float cprev = c_loc[b][j];
            const float iv = sigf(pi), fv = sigf(pf), gv = tanh_(pg);
            float cn = fv * cprev + iv * gv;
            float ov = sigf(po + cn);
            float hn = ov * tanh_(cn);
            if (t >= my_len) { hn = 0.f; cn = 0.f; }
            c_loc[b][j] = cn;
            const long ob = (long)(b0 + b) * 192512 + (long)t * 1024 + jbase + j;
            out_h[ob] = hn;
            out_c[ob] = cn;
            const int sidx = sl_w * 65536 + (b0 + b) * 1024 + jbase + j;
            unsigned short hb = f2b(hn);
            unsigned short chb = f2b(cn);
            unsigned short clb = f2b(cn - b2f(chb));
            __hip_atomic_store(&hst[sidx], hb, __ATOMIC_RELAXED, __HIP_MEMORY_SCOPE_AGENT);
            __hip_atomic_store(&cst[sidx], chb, __ATOMIC_RELAXED, __HIP_MEMORY_SCOPE_AGENT);
            __hip_atomic_store(&cstlo[sidx], clb, __ATOMIC_RELAXED, __HIP_MEMORY_SCOPE_AGENT);
        }
        __threadfence();  // release side: drain this wave's state stores
        if (lane == 0)
            __hip_atomic_store(&flags[cu * 4 + wv], t + 1, __ATOMIC_RELEASE, __HIP_MEMORY_SCOPE_AGENT);
    }
}

// ---------------------------------------------------------------------------
extern "C" void kernel_launch(void* const* d_in, const int* in_sizes, int n_in,
                              void* d_out, int out_size, void* d_ws, size_t ws_size,
                              hipStream_t stream) {
    const float* x    = (const float*)d_in[0];
    const float* h0   = (const float*)d_in[1];
    const float* c0   = (const float*)d_in[2];
    const float* wih  = (const float*)d_in[3];
    const float* whh  = (const float*)d_in[4];
    const float* wrec = (const float*)d_in[5];
    const float* bias = (const float*)d_in[6];
    const int* lengths = (const int*)d_in[7];

    char* ws = (char*)d_ws;
    unsigned short* px     = (unsigned short*)(ws + WS_PX);
    unsigned short* xb     = (unsigned short*)(ws + WS_XB);
    unsigned short* wihb   = (unsigned short*)(ws + WS_WIHB);
    unsigned short* wcomb  = (unsigned short*)(ws + WS_WCOMB);
    unsigned short* hst    = (unsigned short*)(ws + WS_HST);
    unsigned short* cst    = (unsigned short*)(ws + WS_CST);
    unsigned short* wreclo = (unsigned short*)(ws + WS_WRECLO);
    unsigned short* cstlo  = (unsigned short*)(ws + WS_CSTLO);
    int* flags             = (int*)(ws + WS_FLAGS);
    float* out = (float*)d_out;

    hipLaunchKernelGGL(k_prep, dim3(2048), dim3(256), 0, stream,
                       x, h0, c0, wih, whh, wrec, xb, wihb, wcomb, hst, cst, wreclo, cstlo, flags);
    hipLaunchKernelGGL(k_px, dim3(64, 188), dim3(256), 0, stream, xb, wihb, bias, px);
    // REGULAR launch (not cooperative): 256 blocks, 1/CU via launch_bounds(256,1);
    // hand-rolled flag sync handles cross-CU ordering, no grid.sync() used.
    hipLaunchKernelGGL(k_scan, dim3(256), dim3(256), 0, stream,
                       wcomb, wreclo, c0, lengths, px, hst, cst, cstlo, flags, out);
}

// Round 4
// 3698.282 us; speedup vs baseline: 3.0017x; 3.0017x over previous
//
#include <hip/hip_runtime.h>

// ---------------------------------------------------------------------------
// XiRNN (peephole LSTM) on MI355X.  B=64, T=188, I=512, H=R=1024.
//   k_prep : fp32->bf16 conversion; W_rec split into bf16 hi+lo; zero flags.
//   k_px   : px[t][gate][j][b] = x[b,t,:]·W_ih[gate*H+j,:] + bias (MFMA GEMM)
//   k_scan : persistent kernel, 256 blocks (1/CU, regular launch), 4 batch-
//            groups of 16 rows x 64 CUs. Weights register-resident. Peephole
//            in compensated bf16: c_hi@W_hi + c_hi@W_lo + c_lo@W_hi (c runs
//            to ~450). c kept fp32 in LDS locally; cross-CU state in bf16
//            (c split hi/lo) via agent-scope atomics (device-coherent point,
//            bypasses non-coherent per-XCD L2s).
//   R4 change: NO __threadfence() in the step loop. R3's fences compiled to
//   buffer_wbl2/buffer_inv (whole-L2 writeback+invalidate), serializing at
//   each XCD's L2: ~56us/step, and re-fetching px every step (FETCH 4x).
//   Release ordering = s_waitcnt vmcnt(0) before the flag store (all state
//   stores are sc-flagged and complete at the coherent point); acquire needs
//   nothing (state loads are agent-scope, issued after flag observed).
// ---------------------------------------------------------------------------

#define T_N 188

// ws byte offsets (256-aligned). Total = 132,648,960 B (~126.5 MiB).
#define WS_PX     0UL           // ushort[188*4096*64]   = 98,566,144 B
#define WS_XB     98566144UL    // ushort[64*188*512]    = 12,320,768 B
#define WS_WIHB   110886912UL   // ushort[4096*512]      =  4,194,304 B
#define WS_WCOMB  115081216UL   // ushort[6144*1024]     = 12,582,912 B
#define WS_HST    127664128UL   // ushort[2][64][1024]   =    262,144 B
#define WS_CST    127926272UL   // ushort[2][64][1024]   =    262,144 B
#define WS_FLAGS  128188416UL   // int[1024]             =      4,096 B
#define WS_WRECLO 128192512UL   // ushort[2048*1024]     =  4,194,304 B
#define WS_CSTLO  132386816UL   // ushort[2][64][1024]   =    262,144 B

typedef __attribute__((ext_vector_type(8))) short short8;
typedef __attribute__((ext_vector_type(4))) float f4;

__device__ __forceinline__ float b2f(unsigned short u) {
    union { unsigned int i; float f; } v; v.i = ((unsigned int)u) << 16; return v.f;
}
__device__ __forceinline__ unsigned short f2b(float f) {
    unsigned int u = __float_as_uint(f);
    return (unsigned short)((u + 0x7FFFu + ((u >> 16) & 1u)) >> 16);
}
__device__ __forceinline__ float sigf(float x) { return 1.0f / (1.0f + __expf(-x)); }
__device__ __forceinline__ float tanh_(float x) {
    float e = __expf(2.0f * x); return 1.0f - 2.0f / (e + 1.0f);
}
#define MFMA(a, b, c) __builtin_amdgcn_mfma_f32_16x16x32_bf16((a), (b), (c), 0, 0, 0)

// 16B state load through the device-coherent point (bypasses stale L1/L2)
__device__ __forceinline__ short8 ld_state(const unsigned short* p) {
    union { unsigned long long u[2]; short8 v; } r;
    r.u[0] = __hip_atomic_load((unsigned long long*)p,     __ATOMIC_RELAXED, __HIP_MEMORY_SCOPE_AGENT);
    r.u[1] = __hip_atomic_load((unsigned long long*)p + 1, __ATOMIC_RELAXED, __HIP_MEMORY_SCOPE_AGENT);
    return r.v;
}

__device__ __forceinline__ f4 px_init(const unsigned short* px, int t, int gate, int jg, int brow) {
    unsigned long long pv =
        *(const unsigned long long*)(px + ((long)(t * 4 + gate) * 1024 + jg) * 64 + brow);
    f4 r;
    r[0] = b2f((unsigned short)pv);
    r[1] = b2f((unsigned short)(pv >> 16));
    r[2] = b2f((unsigned short)(pv >> 32));
    r[3] = b2f((unsigned short)(pv >> 48));
    return r;
}

// ---------------------------------------------------------------------------
__global__ void k_prep(const float* __restrict__ x, const float* __restrict__ h0,
                       const float* __restrict__ c0, const float* __restrict__ wih,
                       const float* __restrict__ whh, const float* __restrict__ wrec,
                       unsigned short* __restrict__ xb, unsigned short* __restrict__ wihb,
                       unsigned short* __restrict__ wcomb, unsigned short* __restrict__ hst,
                       unsigned short* __restrict__ cst, unsigned short* __restrict__ wreclo,
                       unsigned short* __restrict__ cstlo, int* __restrict__ flags) {
    const long NX4 = 1540096, NWIH4 = 524288, NWHH4 = 1048576, NWREC4 = 524288, NH4 = 16384;
    const long total = NX4 + NWIH4 + NWHH4 + NWREC4 + NH4 + NH4;
    long gtid = (long)blockIdx.x * blockDim.x + threadIdx.x;
    for (long i = gtid; i < total; i += (long)gridDim.x * blockDim.x) {
        const float* src; unsigned short* dst; unsigned short* lo_dst = nullptr; long off = i;
        if (off < NX4)                   { src = x;    dst = xb; }
        else if ((off -= NX4) < NWIH4)   { src = wih;  dst = wihb; }
        else if ((off -= NWIH4) < NWHH4) { src = whh;  dst = wcomb; }
        else if ((off -= NWHH4) < NWREC4){ src = wrec; dst = wcomb + 4194304; lo_dst = wreclo; }
        else if ((off -= NWREC4) < NH4)  { src = h0;   dst = hst + 65536; }     // state slot 1
        else { off -= NH4;                 src = c0;   dst = cst + 65536; lo_dst = cstlo + 65536; }
        float4 v = ((const float4*)src)[off];
        unsigned short hx = f2b(v.x), hy = f2b(v.y), hz = f2b(v.z), hw = f2b(v.w);
        unsigned long long o = (unsigned long long)hx
            | ((unsigned long long)hy << 16)
            | ((unsigned long long)hz << 32)
            | ((unsigned long long)hw << 48);
        *(unsigned long long*)(dst + off * 4) = o;
        if (lo_dst) {
            unsigned long long l = (unsigned long long)f2b(v.x - b2f(hx))
                | ((unsigned long long)f2b(v.y - b2f(hy)) << 16)
                | ((unsigned long long)f2b(v.z - b2f(hz)) << 32)
                | ((unsigned long long)f2b(v.w - b2f(hw)) << 48);
            *(unsigned long long*)(lo_dst + off * 4) = l;
        }
    }
    if (gtid < 1024) flags[gtid] = 0;
}

// ---------------------------------------------------------------------------
// px GEMM: block = (t, 64-col slab), 4 waves, each wave one 16-col tile, M=64.
__global__ void __launch_bounds__(256) k_px(const unsigned short* __restrict__ xb,
                                            const unsigned short* __restrict__ wihb,
                                            const float* __restrict__ bias,
                                            unsigned short* __restrict__ px) {
    const int t = blockIdx.y;
    const int wv = threadIdx.x >> 6, lane = threadIdx.x & 63;
    const int col = lane & 15, quad = lane >> 4;
    const int n = blockIdx.x * 64 + wv * 16 + col;   // 0..4095 combined gate*H+j
    const float bn = bias[n];
    f4 acc[4];
#pragma unroll
    for (int mt = 0; mt < 4; ++mt) { acc[mt][0] = bn; acc[mt][1] = bn; acc[mt][2] = bn; acc[mt][3] = bn; }
    const unsigned short* bp = wihb + n * 512 + quad * 8;
#pragma unroll 4
    for (int kk = 0; kk < 16; ++kk) {
        short8 bf = *(const short8*)(bp + kk * 32);
#pragma unroll
        for (int mt = 0; mt < 4; ++mt) {
            const unsigned short* ap = xb + ((mt * 16 + col) * 188 + t) * 512 + kk * 32 + quad * 8;
            short8 af = *(const short8*)ap;
            acc[mt] = MFMA(af, bf, acc[mt]);
        }
    }
    const long pb = ((long)(t * 4 + (n >> 10)) * 1024 + (n & 1023)) * 64;
#pragma unroll
    for (int mt = 0; mt < 4; ++mt) {
        unsigned long long o = (unsigned long long)f2b(acc[mt][0])
            | ((unsigned long long)f2b(acc[mt][1]) << 16)
            | ((unsigned long long)f2b(acc[mt][2]) << 32)
            | ((unsigned long long)f2b(acc[mt][3]) << 48);
        *(unsigned long long*)(px + pb + mt * 16 + quad * 4) = o;
    }
}

// ---------------------------------------------------------------------------
// Persistent scan. cu = blockIdx: group g = cu>>6 (16 batch rows), cig = cu&63
// (16 hidden indices). 4 waves: kh = wv>>1 (K-half), ts = wv&1.
//   ts0: tiles {i,f,g,o}, A = h (bf16), W rows 0..4095.
//   ts1: tiles {ri,rf} compensated: c_hi@W_hi + c_hi@W_lo + c_lo@W_hi.
__global__ void __launch_bounds__(256, 1) k_scan(
    const unsigned short* __restrict__ wcomb, const unsigned short* __restrict__ wreclo,
    const float* __restrict__ c0, const int* __restrict__ lengths,
    const unsigned short* __restrict__ px, unsigned short* __restrict__ hst,
    unsigned short* __restrict__ cst, unsigned short* __restrict__ cstlo,
    int* __restrict__ flags, float* __restrict__ out) {
    const int cu = blockIdx.x;
    const int g = cu >> 6, cig = cu & 63;
    const int jbase = cig * 16, b0 = g * 16;
    const int tid = threadIdx.x, wv = tid >> 6, lane = tid & 63;
    const int kh = wv >> 1, ts = wv & 1;
    const int kbase = kh * 512;
    const int col = lane & 15, quad = lane >> 4;

    __shared__ float pre[2][2][6][16][16];   // [slot][kh][tile][b][j]  24 KB
    __shared__ float c_loc[16][16];          // fp32 local c (never rounded)

    // One-time: weights -> regs (4 tiles x 16 k-chunks x 16B/lane)
    short8 wf[4][16];
#pragma unroll
    for (int tile = 0; tile < 4; ++tile) {
        // ts0: rows {0,1,2,3}*1024 (i,f,g,o from W_hh).
        // ts1: wf[0]=ri_hi (row 4096+), wf[1]=rf_hi (row 5120+),
        //      wf[2]=ri_lo, wf[3]=rf_lo (from wreclo rows 0/1024).
        const unsigned short* src;
        if (ts == 0) {
            src = wcomb + (long)(tile * 1024 + jbase + col) * 1024 + kbase + quad * 8;
        } else if (tile < 2) {
            src = wcomb + (long)((4 + tile) * 1024 + jbase + col) * 1024 + kbase + quad * 8;
        } else {
            src = wreclo + (long)((tile - 2) * 1024 + jbase + col) * 1024 + kbase + quad * 8;
        }
#pragma unroll
        for (int kk = 0; kk < 16; ++kk) wf[tile][kk] = *(const short8*)(src + kk * 32);
    }
    {
        int b = tid >> 4, j = tid & 15;
        c_loc[b][j] = c0[(b0 + b) * 1024 + jbase + j];
    }
    const int my_len = lengths[b0 + (tid >> 4)];
    __syncthreads();

    const int fl_base = g * 256;             // this group's 64 CUs x 4 wave-flags
    float* out_h = out;
    float* out_c = out + 12320768;

    for (int t = 0; t < T_N; ++t) {
        const int sl_r = (t + 1) & 1, sl_w = t & 1, ps = t & 1;

        if (t > 0) {
            int* fp = flags + fl_base + lane * 4;
            for (;;) {
                int a0 = __hip_atomic_load(fp + 0, __ATOMIC_RELAXED, __HIP_MEMORY_SCOPE_AGENT);
                int a1 = __hip_atomic_load(fp + 1, __ATOMIC_RELAXED, __HIP_MEMORY_SCOPE_AGENT);
                int a2 = __hip_atomic_load(fp + 2, __ATOMIC_RELAXED, __HIP_MEMORY_SCOPE_AGENT);
                int a3 = __hip_atomic_load(fp + 3, __ATOMIC_RELAXED, __HIP_MEMORY_SCOPE_AGENT);
                if (__all((a0 >= t) && (a1 >= t) && (a2 >= t) && (a3 >= t))) break;
                __builtin_amdgcn_s_sleep(1);
            }
            // compiler barrier: keep state loads below the poll (no fence needed:
            // producer drained vmcnt before posting; our loads are agent-scope)
            asm volatile("" ::: "memory");
        }

        const int sbase = sl_r * 65536 + (b0 + col) * 1024 + kbase + quad * 8;

        if (ts == 0) {
            const unsigned short* hp = hst + sbase;
            f4 acc[4];
#pragma unroll
            for (int tile = 0; tile < 4; ++tile) {
                if (kh == 0) acc[tile] = px_init(px, t, tile, jbase + col, b0 + quad * 4);
                else { acc[tile][0] = 0.f; acc[tile][1] = 0.f; acc[tile][2] = 0.f; acc[tile][3] = 0.f; }
            }
#pragma unroll
            for (int kk = 0; kk < 16; ++kk) {
                short8 af = ld_state(hp + kk * 32);
                acc[0] = MFMA(af, wf[0][kk], acc[0]);
                acc[1] = MFMA(af, wf[1][kk], acc[1]);
                acc[2] = MFMA(af, wf[2][kk], acc[2]);
                acc[3] = MFMA(af, wf[3][kk], acc[3]);
            }
#pragma unroll
            for (int tile = 0; tile < 4; ++tile)
#pragma unroll
                for (int r = 0; r < 4; ++r) pre[ps][kh][tile][quad * 4 + r][col] = acc[tile][r];
        } else {
            const unsigned short* cph = cst + sbase;
            const unsigned short* cpl = cstlo + sbase;
            f4 acc[2];
            acc[0][0] = 0.f; acc[0][1] = 0.f; acc[0][2] = 0.f; acc[0][3] = 0.f;
            acc[1][0] = 0.f; acc[1][1] = 0.f; acc[1][2] = 0.f; acc[1][3] = 0.f;
#pragma unroll
            for (int kk = 0; kk < 16; ++kk) {
                short8 ch = ld_state(cph + kk * 32);
                short8 cl = ld_state(cpl + kk * 32);
                acc[0] = MFMA(ch, wf[0][kk], acc[0]);   // c_hi @ ri_hi
                acc[0] = MFMA(ch, wf[2][kk], acc[0]);   // c_hi @ ri_lo
                acc[0] = MFMA(cl, wf[0][kk], acc[0]);   // c_lo @ ri_hi
                acc[1] = MFMA(ch, wf[1][kk], acc[1]);   // c_hi @ rf_hi
                acc[1] = MFMA(ch, wf[3][kk], acc[1]);   // c_hi @ rf_lo
                acc[1] = MFMA(cl, wf[1][kk], acc[1]);   // c_lo @ rf_hi
            }
#pragma unroll
            for (int tile = 0; tile < 2; ++tile)
#pragma unroll
                for (int r = 0; r < 4; ++r) pre[ps][kh][4 + tile][quad * 4 + r][col] = acc[tile][r];
        }
        __syncthreads();
        {
            const int b = tid >> 4, j = tid & 15;
            float pi = pre[ps][0][0][b][j] + pre[ps][1][0][b][j] + pre[ps][0][4][b][j] + pre[ps][1][4][b][j];
            float pf = pre[ps][0][1][b][j] + pre[ps][1][1][b][j] + pre[ps][0][5][b][j] + pre[ps][1][5][b][j];
            float pg = pre[ps][0][2][b][j] + pre[ps][1][2][b][j];
            float po = pre[ps][0][3][b][j] + pre[ps][1][3][b][j];
            const float cprev = c_loc[b][j];
            const float iv = sigf(pi), fv = sigf(pf), gv = tanh_(pg);
            float cn = fv * cprev + iv * gv;
            float ov = sigf(po + cn);
            float hn = ov * tanh_(cn);
            if (t >= my_len) { hn = 0.f; cn = 0.f; }
            c_loc[b][j] = cn;
            const long ob = (long)(b0 + b) * 192512 + (long)t * 1024 + jbase + j;
            out_h[ob] = hn;
            out_c[ob] = cn;
            const int sidx = sl_w * 65536 + (b0 + b) * 1024 + jbase + j;
            unsigned short hb = f2b(hn);
            unsigned short chb = f2b(cn);
            unsigned short clb = f2b(cn - b2f(chb));
            __hip_atomic_store(&hst[sidx], hb, __ATOMIC_RELAXED, __HIP_MEMORY_SCOPE_AGENT);
            __hip_atomic_store(&cst[sidx], chb, __ATOMIC_RELAXED, __HIP_MEMORY_SCOPE_AGENT);
            __hip_atomic_store(&cstlo[sidx], clb, __ATOMIC_RELAXED, __HIP_MEMORY_SCOPE_AGENT);
        }
        // Release: drain this wave's state stores (they complete at the
        // coherent point), then post flag. NO L2 writeback fence.
        asm volatile("s_waitcnt vmcnt(0)" ::: "memory");
        if (lane == 0)
            __hip_atomic_store(&flags[cu * 4 + wv], t + 1, __ATOMIC_RELAXED, __HIP_MEMORY_SCOPE_AGENT);
    }
}

// ---------------------------------------------------------------------------
extern "C" void kernel_launch(void* const* d_in, const int* in_sizes, int n_in,
                              void* d_out, int out_size, void* d_ws, size_t ws_size,
                              hipStream_t stream) {
    const float* x    = (const float*)d_in[0];
    const float* h0   = (const float*)d_in[1];
    const float* c0   = (const float*)d_in[2];
    const float* wih  = (const float*)d_in[3];
    const float* whh  = (const float*)d_in[4];
    const float* wrec = (const float*)d_in[5];
    const float* bias = (const float*)d_in[6];
    const int* lengths = (const int*)d_in[7];

    char* ws = (char*)d_ws;
    unsigned short* px     = (unsigned short*)(ws + WS_PX);
    unsigned short* xb     = (unsigned short*)(ws + WS_XB);
    unsigned short* wihb   = (unsigned short*)(ws + WS_WIHB);
    unsigned short* wcomb  = (unsigned short*)(ws + WS_WCOMB);
    unsigned short* hst    = (unsigned short*)(ws + WS_HST);
    unsigned short* cst    = (unsigned short*)(ws + WS_CST);
    unsigned short* wreclo = (unsigned short*)(ws + WS_WRECLO);
    unsigned short* cstlo  = (unsigned short*)(ws + WS_CSTLO);
    int* flags             = (int*)(ws + WS_FLAGS);
    float* out = (float*)d_out;

    hipLaunchKernelGGL(k_prep, dim3(2048), dim3(256), 0, stream,
                       x, h0, c0, wih, whh, wrec, xb, wihb, wcomb, hst, cst, wreclo, cstlo, flags);
    hipLaunchKernelGGL(k_px, dim3(64, 188), dim3(256), 0, stream, xb, wihb, bias, px);
    hipLaunchKernelGGL(k_scan, dim3(256), dim3(256), 0, stream,
                       wcomb, wreclo, c0, lengths, px, hst, cst, cstlo, flags, out);
}

// Round 7
// 2075.116 us; speedup vs baseline: 5.3496x; 1.7822x over previous
//
#include <hip/hip_runtime.h>

// ---------------------------------------------------------------------------
// XiRNN (peephole LSTM) on MI355X.  B=64, T=188, I=512, H=R=1024.
//   k_prep : fp32->bf16 conversion; W_rec split into bf16 hi+lo; zero flags.
//   k_px   : px[t][gate][j][b] = x[b,t,:]·W_ih[gate*H+j,:] + bias (MFMA GEMM)
//   k_scan : persistent kernel, 256 blocks (1/CU), 4 batch-groups of 16 rows
//            x 64 CUs. Weights register-resident. Peephole in compensated
//            bf16: c_hi@W_hi + c_hi@W_lo + c_lo@W_hi (c runs to ~450). c kept
//            fp32 in LDS locally; cross-CU state in bf16 (c hi/lo).
//   R4: removed __threadfence (buffer_wbl2/inv serialization): 56->16.8us/step.
//   R5/R6 FAILED (bit-identical 0.289 across different sync mechanisms =>
//   deterministic math bug, not a race): the px hoist seeded the ri peephole
//   accumulator with the o-gate px (pi got a spurious +px_o). Sync was fine.
//   R7: fix the seed (ts1 loads NO px; o-gate px lives only in ts0 tile 3).
//   Publish state with plain relaxed agent-scope stores (R4-proven); keep
//   R5's lean sync: all waves vmcnt(0)-drain -> barrier -> ONE flag per CU,
//   wave0-only poll; out stores after flag post; px loads (ts0) hoisted
//   above the poll.
// ---------------------------------------------------------------------------

#define T_N 188

// ws byte offsets (256-aligned). Total = 132,648,960 B (~126.5 MiB).
#define WS_PX     0UL           // ushort[188*4096*64]   = 98,566,144 B
#define WS_XB     98566144UL    // ushort[64*188*512]    = 12,320,768 B
#define WS_WIHB   110886912UL   // ushort[4096*512]      =  4,194,304 B
#define WS_WCOMB  115081216UL   // ushort[6144*1024]     = 12,582,912 B
#define WS_HST    127664128UL   // ushort[2][64][1024]   =    262,144 B
#define WS_CST    127926272UL   // ushort[2][64][1024]   =    262,144 B
#define WS_FLAGS  128188416UL   // int[1024]             =      4,096 B
#define WS_WRECLO 128192512UL   // ushort[2048*1024]     =  4,194,304 B
#define WS_CSTLO  132386816UL   // ushort[2][64][1024]   =    262,144 B

typedef __attribute__((ext_vector_type(8))) short short8;
typedef __attribute__((ext_vector_type(4))) float f4;

__device__ __forceinline__ float b2f(unsigned short u) {
    union { unsigned int i; float f; } v; v.i = ((unsigned int)u) << 16; return v.f;
}
__device__ __forceinline__ unsigned short f2b(float f) {
    unsigned int u = __float_as_uint(f);
    return (unsigned short)((u + 0x7FFFu + ((u >> 16) & 1u)) >> 16);
}
__device__ __forceinline__ float sigf(float x) { return 1.0f / (1.0f + __expf(-x)); }
__device__ __forceinline__ float tanh_(float x) {
    float e = __expf(2.0f * x); return 1.0f - 2.0f / (e + 1.0f);
}
#define MFMA(a, b, c) __builtin_amdgcn_mfma_f32_16x16x32_bf16((a), (b), (c), 0, 0, 0)

// 16B state load through the device-coherent point (bypasses stale L1/L2)
__device__ __forceinline__ short8 ld_state(const unsigned short* p) {
    union { unsigned long long u[2]; short8 v; } r;
    r.u[0] = __hip_atomic_load((unsigned long long*)p,     __ATOMIC_RELAXED, __HIP_MEMORY_SCOPE_AGENT);
    r.u[1] = __hip_atomic_load((unsigned long long*)p + 1, __ATOMIC_RELAXED, __HIP_MEMORY_SCOPE_AGENT);
    return r.v;
}

__device__ __forceinline__ f4 px_init(const unsigned short* px, int t, int gate, int jg, int brow) {
    unsigned long long pv =
        *(const unsigned long long*)(px + ((long)(t * 4 + gate) * 1024 + jg) * 64 + brow);
    f4 r;
    r[0] = b2f((unsigned short)pv);
    r[1] = b2f((unsigned short)(pv >> 16));
    r[2] = b2f((unsigned short)(pv >> 32));
    r[3] = b2f((unsigned short)(pv >> 48));
    return r;
}

// ---------------------------------------------------------------------------
__global__ void k_prep(const float* __restrict__ x, const float* __restrict__ h0,
                       const float* __restrict__ c0, const float* __restrict__ wih,
                       const float* __restrict__ whh, const float* __restrict__ wrec,
                       unsigned short* __restrict__ xb, unsigned short* __restrict__ wihb,
                       unsigned short* __restrict__ wcomb, unsigned short* __restrict__ hst,
                       unsigned short* __restrict__ cst, unsigned short* __restrict__ wreclo,
                       unsigned short* __restrict__ cstlo, int* __restrict__ flags) {
    const long NX4 = 1540096, NWIH4 = 524288, NWHH4 = 1048576, NWREC4 = 524288, NH4 = 16384;
    const long total = NX4 + NWIH4 + NWHH4 + NWREC4 + NH4 + NH4;
    long gtid = (long)blockIdx.x * blockDim.x + threadIdx.x;
    for (long i = gtid; i < total; i += (long)gridDim.x * blockDim.x) {
        const float* src; unsigned short* dst; unsigned short* lo_dst = nullptr; long off = i;
        if (off < NX4)                   { src = x;    dst = xb; }
        else if ((off -= NX4) < NWIH4)   { src = wih;  dst = wihb; }
        else if ((off -= NWIH4) < NWHH4) { src = whh;  dst = wcomb; }
        else if ((off -= NWHH4) < NWREC4){ src = wrec; dst = wcomb + 4194304; lo_dst = wreclo; }
        else if ((off -= NWREC4) < NH4)  { src = h0;   dst = hst + 65536; }     // state slot 1
        else { off -= NH4;                 src = c0;   dst = cst + 65536; lo_dst = cstlo + 65536; }
        float4 v = ((const float4*)src)[off];
        unsigned short hx = f2b(v.x), hy = f2b(v.y), hz = f2b(v.z), hw = f2b(v.w);
        unsigned long long o = (unsigned long long)hx
            | ((unsigned long long)hy << 16)
            | ((unsigned long long)hz << 32)
            | ((unsigned long long)hw << 48);
        *(unsigned long long*)(dst + off * 4) = o;
        if (lo_dst) {
            unsigned long long l = (unsigned long long)f2b(v.x - b2f(hx))
                | ((unsigned long long)f2b(v.y - b2f(hy)) << 16)
                | ((unsigned long long)f2b(v.z - b2f(hz)) << 32)
                | ((unsigned long long)f2b(v.w - b2f(hw)) << 48);
            *(unsigned long long*)(lo_dst + off * 4) = l;
        }
    }
    if (gtid < 1024) flags[gtid] = 0;
}

// ---------------------------------------------------------------------------
// px GEMM: block = (t, 64-col slab), 4 waves, each wave one 16-col tile, M=64.
__global__ void __launch_bounds__(256) k_px(const unsigned short* __restrict__ xb,
                                            const unsigned short* __restrict__ wihb,
                                            const float* __restrict__ bias,
                                            unsigned short* __restrict__ px) {
    const int t = blockIdx.y;
    const int wv = threadIdx.x >> 6, lane = threadIdx.x & 63;
    const int col = lane & 15, quad = lane >> 4;
    const int n = blockIdx.x * 64 + wv * 16 + col;   // 0..4095 combined gate*H+j
    const float bn = bias[n];
    f4 acc[4];
#pragma unroll
    for (int mt = 0; mt < 4; ++mt) { acc[mt][0] = bn; acc[mt][1] = bn; acc[mt][2] = bn; acc[mt][3] = bn; }
    const unsigned short* bp = wihb + n * 512 + quad * 8;
#pragma unroll 4
    for (int kk = 0; kk < 16; ++kk) {
        short8 bf = *(const short8*)(bp + kk * 32);
#pragma unroll
        for (int mt = 0; mt < 4; ++mt) {
            const unsigned short* ap = xb + ((mt * 16 + col) * 188 + t) * 512 + kk * 32 + quad * 8;
            short8 af = *(const short8*)ap;
            acc[mt] = MFMA(af, bf, acc[mt]);
        }
    }
    const long pb = ((long)(t * 4 + (n >> 10)) * 1024 + (n & 1023)) * 64;
#pragma unroll
    for (int mt = 0; mt < 4; ++mt) {
        unsigned long long o = (unsigned long long)f2b(acc[mt][0])
            | ((unsigned long long)f2b(acc[mt][1]) << 16)
            | ((unsigned long long)f2b(acc[mt][2]) << 32)
            | ((unsigned long long)f2b(acc[mt][3]) << 48);
        *(unsigned long long*)(px + pb + mt * 16 + quad * 4) = o;
    }
}

// ---------------------------------------------------------------------------
// Persistent scan. cu = blockIdx: group g = cu>>6 (16 batch rows), cig = cu&63
// (16 hidden indices). 4 waves: kh = wv>>1 (K-half), ts = wv&1.
//   ts0: tiles {i,f,g,o}, A = h (bf16), px gates 0..3 seeded at kh==0.
//   ts1: tiles {ri,rf} compensated (c_hi@W_hi + c_hi@W_lo + c_lo@W_hi),
//        seeded ZERO — peephole tiles carry no px term.
__global__ void __launch_bounds__(256, 1) k_scan(
    const unsigned short* __restrict__ wcomb, const unsigned short* __restrict__ wreclo,
    const float* __restrict__ c0, const int* __restrict__ lengths,
    const unsigned short* __restrict__ px, unsigned short* __restrict__ hst,
    unsigned short* __restrict__ cst, unsigned short* __restrict__ cstlo,
    int* __restrict__ flags, float* __restrict__ out) {
    const int cu = blockIdx.x;
    const int g = cu >> 6, cig = cu & 63;
    const int jbase = cig * 16, b0 = g * 16;
    const int tid = threadIdx.x, wv = tid >> 6, lane = tid & 63;
    const int kh = wv >> 1, ts = wv & 1;
    const int kbase = kh * 512;
    const int col = lane & 15, quad = lane >> 4;

    __shared__ float pre[2][2][6][16][16];   // [slot][kh][tile][b][j]  24 KB
    __shared__ float c_loc[16][16];          // fp32 local c (never rounded)

    // One-time: weights -> regs (4 tiles x 16 k-chunks x 16B/lane)
    short8 wf[4][16];
#pragma unroll
    for (int tile = 0; tile < 4; ++tile) {
        // ts0: rows {0,1,2,3}*1024 (i,f,g,o from W_hh).
        // ts1: wf[0]=ri_hi (row 4096+), wf[1]=rf_hi (row 5120+),
        //      wf[2]=ri_lo, wf[3]=rf_lo (from wreclo rows 0/1024).
        const unsigned short* src;
        if (ts == 0) {
            src = wcomb + (long)(tile * 1024 + jbase + col) * 1024 + kbase + quad * 8;
        } else if (tile < 2) {
            src = wcomb + (long)((4 + tile) * 1024 + jbase + col) * 1024 + kbase + quad * 8;
        } else {
            src = wreclo + (long)((tile - 2) * 1024 + jbase + col) * 1024 + kbase + quad * 8;
        }
#pragma unroll
        for (int kk = 0; kk < 16; ++kk) wf[tile][kk] = *(const short8*)(src + kk * 32);
    }
    {
        int b = tid >> 4, j = tid & 15;
        c_loc[b][j] = c0[(b0 + b) * 1024 + jbase + j];
    }
    const int my_len = lengths[b0 + (tid >> 4)];
    __syncthreads();

    float* out_h = out;
    float* out_c = out + 12320768;

    for (int t = 0; t < T_N; ++t) {
        const int sl_r = (t + 1) & 1, sl_w = t & 1, ps = t & 1;

        // px loads (ts0/kh0 only — gates 0..3) are state-independent: issue
        // before the wait so they're in flight while we poll.
        f4 pxv[4];
        if (ts == 0 && kh == 0) {
#pragma unroll
            for (int tile = 0; tile < 4; ++tile)
                pxv[tile] = px_init(px, t, tile, jbase + col, b0 + quad * 4);
        }

        if (t > 0) {
            // Only wave 0 polls (lane i watches CU i of this group): 64
            // agent-scope transactions per iteration per CU.
            if (wv == 0) {
                const int* fp = flags + g * 64 + lane;
                for (;;) {
                    int a = __hip_atomic_load(fp, __ATOMIC_RELAXED, __HIP_MEMORY_SCOPE_AGENT);
                    if (__all(a >= t)) break;
                    __builtin_amdgcn_s_sleep(1);
                }
            }
            __syncthreads();   // release whole block once wave 0 saw all flags
            asm volatile("" ::: "memory");
        }

        const int sbase = sl_r * 65536 + (b0 + col) * 1024 + kbase + quad * 8;

        if (ts == 0) {
            const unsigned short* hp = hst + sbase;
            f4 acc[4];
#pragma unroll
            for (int tile = 0; tile < 4; ++tile) {
                if (kh == 0) acc[tile] = pxv[tile];
                else { acc[tile][0] = 0.f; acc[tile][1] = 0.f; acc[tile][2] = 0.f; acc[tile][3] = 0.f; }
            }
#pragma unroll
            for (int kk = 0; kk < 16; ++kk) {
                short8 af = ld_state(hp + kk * 32);
                acc[0] = MFMA(af, wf[0][kk], acc[0]);
                acc[1] = MFMA(af, wf[1][kk], acc[1]);
                acc[2] = MFMA(af, wf[2][kk], acc[2]);
                acc[3] = MFMA(af, wf[3][kk], acc[3]);
            }
#pragma unroll
            for (int tile = 0; tile < 4; ++tile)
#pragma unroll
                for (int r = 0; r < 4; ++r) pre[ps][kh][tile][quad * 4 + r][col] = acc[tile][r];
        } else {
            const unsigned short* cph = cst + sbase;
            const unsigned short* cpl = cstlo + sbase;
            f4 acc[2];
            // Peephole tiles: ZERO seed (px_o lives in ts0 tile 3 only —
            // seeding px here was the R5/R6 bug).
            acc[0][0] = 0.f; acc[0][1] = 0.f; acc[0][2] = 0.f; acc[0][3] = 0.f;
            acc[1][0] = 0.f; acc[1][1] = 0.f; acc[1][2] = 0.f; acc[1][3] = 0.f;
#pragma unroll
            for (int kk = 0; kk < 16; ++kk) {
                short8 ch = ld_state(cph + kk * 32);
                short8 cl = ld_state(cpl + kk * 32);
                acc[0] = MFMA(ch, wf[0][kk], acc[0]);   // c_hi @ ri_hi
                acc[0] = MFMA(ch, wf[2][kk], acc[0]);   // c_hi @ ri_lo
                acc[0] = MFMA(cl, wf[0][kk], acc[0]);   // c_lo @ ri_hi
                acc[1] = MFMA(ch, wf[1][kk], acc[1]);   // c_hi @ rf_hi
                acc[1] = MFMA(ch, wf[3][kk], acc[1]);   // c_hi @ rf_lo
                acc[1] = MFMA(cl, wf[1][kk], acc[1]);   // c_lo @ rf_hi
            }
#pragma unroll
            for (int tile = 0; tile < 2; ++tile)
#pragma unroll
                for (int r = 0; r < 4; ++r) pre[ps][kh][4 + tile][quad * 4 + r][col] = acc[tile][r];
        }
        __syncthreads();

        float hn, cn; long ob;
        {
            const int b = tid >> 4, j = tid & 15;
            float pi = pre[ps][0][0][b][j] + pre[ps][1][0][b][j] + pre[ps][0][4][b][j] + pre[ps][1][4][b][j];
            float pf = pre[ps][0][1][b][j] + pre[ps][1][1][b][j] + pre[ps][0][5][b][j] + pre[ps][1][5][b][j];
            float pg = pre[ps][0][2][b][j] + pre[ps][1][2][b][j];
            float po = pre[ps][0][3][b][j] + pre[ps][1][3][b][j];
            const float cprev = c_loc[b][j];
            const float iv = sigf(pi), fv = sigf(pf), gv = tanh_(pg);
            cn = fv * cprev + iv * gv;
            float ov = sigf(po + cn);
            hn = ov * tanh_(cn);
            if (t >= my_len) { hn = 0.f; cn = 0.f; }
            c_loc[b][j] = cn;
            ob = (long)(b0 + b) * 192512 + (long)t * 1024 + jbase + j;
            const int sidx = sl_w * 65536 + (b0 + b) * 1024 + jbase + j;
            unsigned short hb  = f2b(hn);
            unsigned short chb = f2b(cn);
            unsigned short clb = f2b(cn - b2f(chb));
            __hip_atomic_store(&hst[sidx],  hb,  __ATOMIC_RELAXED, __HIP_MEMORY_SCOPE_AGENT);
            __hip_atomic_store(&cst[sidx],  chb, __ATOMIC_RELAXED, __HIP_MEMORY_SCOPE_AGENT);
            __hip_atomic_store(&cstlo[sidx], clb, __ATOMIC_RELAXED, __HIP_MEMORY_SCOPE_AGENT);
        }
        // Release: each wave drains its own state stores, barrier so all
        // waves' stores are complete, then ONE flag per CU.
        asm volatile("s_waitcnt vmcnt(0)" ::: "memory");
        __syncthreads();
        if (tid == 0)
            __hip_atomic_store(&flags[cu], t + 1, __ATOMIC_RELAXED, __HIP_MEMORY_SCOPE_AGENT);
        // Out stores AFTER the flag post: not consumed by other CUs, so they
        // stay off the critical path (drained by next step's vmcnt(0)).
        out_h[ob] = hn;
        out_c[ob] = cn;
    }
}

// ---------------------------------------------------------------------------
extern "C" void kernel_launch(void* const* d_in, const int* in_sizes, int n_in,
                              void* d_out, int out_size, void* d_ws, size_t ws_size,
                              hipStream_t stream) {
    const float* x    = (const float*)d_in[0];
    const float* h0   = (const float*)d_in[1];
    const float* c0   = (const float*)d_in[2];
    const float* wih  = (const float*)d_in[3];
    const float* whh  = (const float*)d_in[4];
    const float* wrec = (const float*)d_in[5];
    const float* bias = (const float*)d_in[6];
    const int* lengths = (const int*)d_in[7];

    char* ws = (char*)d_ws;
    unsigned short* px     = (unsigned short*)(ws + WS_PX);
    unsigned short* xb     = (unsigned short*)(ws + WS_XB);
    unsigned short* wihb   = (unsigned short*)(ws + WS_WIHB);
    unsigned short* wcomb  = (unsigned short*)(ws + WS_WCOMB);
    unsigned short* hst    = (unsigned short*)(ws + WS_HST);
    unsigned short* cst    = (unsigned short*)(ws + WS_CST);
    unsigned short* wreclo = (unsigned short*)(ws + WS_WRECLO);
    unsigned short* cstlo  = (unsigned short*)(ws + WS_CSTLO);
    int* flags             = (int*)(ws + WS_FLAGS);
    float* out = (float*)d_out;

    hipLaunchKernelGGL(k_prep, dim3(2048), dim3(256), 0, stream,
                       x, h0, c0, wih, whh, wrec, xb, wihb, wcomb, hst, cst, wreclo, cstlo, flags);
    hipLaunchKernelGGL(k_px, dim3(64, 188), dim3(256), 0, stream, xb, wihb, bias, px);
    hipLaunchKernelGGL(k_scan, dim3(256), dim3(256), 0, stream,
                       wcomb, wreclo, c0, lengths, px, hst, cst, cstlo, flags, out);
}